// Round 8
// baseline (5050.058 us; speedup 1.0000x reference)
//
#include <hip/hip_runtime.h>
#include <math.h>

#define B_SZ 1024
#define N_SZ 100000
#define D_SZ 512
#define NBLK 3125   // N/32 row-tiles (exact: 100000 = 3125*32)

typedef __attribute__((ext_vector_type(8))) short short8;
typedef __attribute__((ext_vector_type(16))) float float16;

__device__ __forceinline__ unsigned f2bf(float x) {
    unsigned u = __float_as_uint(x);
    u += 0x7FFFu + ((u >> 16) & 1u);
    return u >> 16;                       // RNE bf16 bits in low 16
}
__device__ __forceinline__ float bf2f(unsigned h) {
    return __uint_as_float(h << 16);
}

// ---------------- PRE: build MFMA-fragment-layout copies of Y ----------------
// Ysh/Ysl[tile][gp 0..31][lane 0..63][8 shorts]: lane L holds row (tile*32+L&31),
// granule gp*2+(L>>5)  -> attn's S A-frag load is one coalesced 1KB dwordx4.
// Yt[tile][d][n'] for the PV A-side. Plus norms and X hi/lo split.
__global__ __launch_bounds__(256) void pre_kernel(
    const float* __restrict__ ds, const float* __restrict__ x_t,
    short* __restrict__ Ysh, short* __restrict__ Ysl, short* __restrict__ Yt,
    short* __restrict__ Xh, short* __restrict__ Xl, float* __restrict__ norms)
{
    __shared__ unsigned short YS[32 * 512];    // hi tile [n][d]
    __shared__ unsigned short YS2[32 * 512];   // lo tile [n][d]
    const int bx = blockIdx.x, tid = threadIdx.x;
    if (bx < NBLK) {
        const int row = tid >> 3, seg = tid & 7;
        const size_t g = (size_t)(bx * 32 + row) * 512 + seg * 64;
        const int ls = row * 512 + seg * 64;
        float nrm = 0.f;
        #pragma unroll
        for (int i = 0; i < 16; i++) {
            float4 v = *(const float4*)(ds + g + i * 4);
            nrm += v.x*v.x + v.y*v.y + v.z*v.z + v.w*v.w;
            unsigned h0 = f2bf(v.x), h1 = f2bf(v.y), h2 = f2bf(v.z), h3 = f2bf(v.w);
            unsigned l0 = f2bf(v.x - bf2f(h0)), l1 = f2bf(v.y - bf2f(h1));
            unsigned l2 = f2bf(v.z - bf2f(h2)), l3 = f2bf(v.w - bf2f(h3));
            *(uint2*)(YS  + ls + i * 4) = make_uint2(h0 | (h1 << 16), h2 | (h3 << 16));
            *(uint2*)(YS2 + ls + i * 4) = make_uint2(l0 | (l1 << 16), l2 | (l3 << 16));
        }
        nrm += __shfl_xor(nrm, 1, 64);
        nrm += __shfl_xor(nrm, 2, 64);
        nrm += __shfl_xor(nrm, 4, 64);
        if ((tid & 7) == 0) norms[bx * 32 + row] = nrm;
        __syncthreads();
        // Yt[bx][d][n'] (rows of 32 bf16 = 64 B)
        #pragma unroll
        for (int r = 0; r < 2; r++) {
            const int d = tid + r * 256;
            unsigned w[16];
            #pragma unroll
            for (int j = 0; j < 16; j++) {
                unsigned lo = YS[(2 * j) * 512 + d];
                unsigned hi = YS[(2 * j + 1) * 512 + d];
                w[j] = lo | (hi << 16);
            }
            uint4* dst = (uint4*)(Yt + (size_t)bx * 16384 + d * 32);
            dst[0] = make_uint4(w[0], w[1], w[2], w[3]);
            dst[1] = make_uint4(w[4], w[5], w[6], w[7]);
            dst[2] = make_uint4(w[8], w[9], w[10], w[11]);
            dst[3] = make_uint4(w[12], w[13], w[14], w[15]);
        }
        // Ysh/Ysl fragment layout: dst linear in idx -> perfectly coalesced
        #pragma unroll
        for (int c = 0; c < 8; c++) {
            int idx = c * 256 + tid;                 // 0..2047
            int n = idx & 31;
            int gran = ((idx >> 6) << 1) | ((idx >> 5) & 1);   // gp*2 + hf
            int src = n * 512 + gran * 8;
            *(uint4*)(Ysh + (size_t)bx * 16384 + idx * 8) = *(const uint4*)(YS  + src);
            *(uint4*)(Ysl + (size_t)bx * 16384 + idx * 8) = *(const uint4*)(YS2 + src);
        }
    } else {
        const int xb = bx - NBLK;   // 0..31, X split: 1024x512 f32
        #pragma unroll
        for (int k = 0; k < 16; k++) {
            const size_t i4 = (size_t)xb * 4096 + k * 256 + tid;
            float4 v = *(const float4*)(x_t + i4 * 4);
            unsigned h0 = f2bf(v.x), h1 = f2bf(v.y), h2 = f2bf(v.z), h3 = f2bf(v.w);
            unsigned l0 = f2bf(v.x - bf2f(h0)), l1 = f2bf(v.y - bf2f(h1));
            unsigned l2 = f2bf(v.z - bf2f(h2)), l3 = f2bf(v.w - bf2f(h3));
            *(uint2*)(Xh + i4 * 4) = make_uint2(h0 | (h1 << 16), h2 | (h3 << 16));
            *(uint2*)(Xl + i4 * 4) = make_uint2(l0 | (l1 << 16), l2 | (l3 << 16));
        }
    }
}

// ---------------- MAIN: merged-wave MFMA flash, no LDS staging ----------------
// 512 thr = 8 waves, Q-tile 32. Each wave: 64-dim k-slice of S^T = Y.X^T
// (3 bf16 passes, A-frags = coalesced global loads from Ysh/Ysl), LDS-atomic
// k-reduce, softmax (waves 0-3), then 64-dim d-slice of O += Yt^T.P^T.
// LDS is tiny (7 KB) -> occupancy set by registers: __launch_bounds__(512,4)
// caps unified VGPR+AGPR at 128/wave -> 2 blocks/CU (all 512 blocks resident).
__global__ __launch_bounds__(512, 4) void attn_kernel(
    const float* __restrict__ t,
    const short* __restrict__ Xh, const short* __restrict__ Xl,
    const short* __restrict__ Ysh, const short* __restrict__ Ysl,
    const short* __restrict__ Yt, const float* __restrict__ norms,
    float* __restrict__ m_part, float* __restrict__ l_part,
    float* __restrict__ acc_part, int chunk)
{
    __shared__ float slots[32 * 33]; // S k-reduce, pitch 33
    __shared__ short Pb[4 * 32 * 8]; // P bf16, [gk][q][8]
    __shared__ float c1A[32], c2A[32], mAs[32], lAs[32], alA[32], nrmL[32];

    const int tid = threadIdx.x;
    const int w = tid >> 6, lane = tid & 63;
    const int half = lane >> 5, l31 = lane & 31;
    const int qb = blockIdx.x * 32;
    const int s = blockIdx.y;
    const int n0s = s * chunk;
    const int n1 = min(N_SZ, n0s + chunk);
    const int numTiles = (n1 - n0s) >> 5;   // chunk%32==0, N%32==0
    const int b0 = n0s >> 5;

    if (tid < 32) {
        float tv = t[qb + tid];
        float bt = 1.0f - tv;
        float i2 = 1.0f / (2.0f * bt * bt);
        c1A[tid] = 2.0f * tv * i2;
        c2A[tid] = tv * tv * i2;
        mAs[tid] = -1e30f;
        lAs[tid] = 0.0f;
        alA[tid] = 0.0f;
    }
    for (int i = tid; i < 32 * 33; i += 512) slots[i] = 0.0f;
    __syncthreads();

    // persistent X fragments: k-slice dims [w*64, w*64+64)
    short8 XF[4][2];
    #pragma unroll
    for (int kc = 0; kc < 4; kc++) {
        size_t off = (size_t)(qb + l31) * 512 + (w * 8 + kc * 2 + half) * 8;
        XF[kc][0] = *(const short8*)(Xh + off);
        XF[kc][1] = *(const short8*)(Xl + off);
    }

    float16 O[2];
    #pragma unroll
    for (int dt = 0; dt < 2; dt++)
        #pragma unroll
        for (int e = 0; e < 16; e++) O[dt][e] = 0.f;

    for (int it = 0; it < numTiles; ++it) {
        const size_t tb = (size_t)(b0 + it) * 16384;
        // ---- S phase: coalesced fragment loads + 12 MFMA ----
        float16 S;
        #pragma unroll
        for (int e = 0; e < 16; e++) S[e] = 0.f;
        #pragma unroll
        for (int kc = 0; kc < 4; kc++) {
            short8 Ah = *(const short8*)(Ysh + tb + (w * 4 + kc) * 512 + lane * 8);
            short8 Al = *(const short8*)(Ysl + tb + (w * 4 + kc) * 512 + lane * 8);
            S = __builtin_amdgcn_mfma_f32_32x32x16_bf16(Ah, XF[kc][0], S, 0, 0, 0);
            S = __builtin_amdgcn_mfma_f32_32x32x16_bf16(Ah, XF[kc][1], S, 0, 0, 0);
            S = __builtin_amdgcn_mfma_f32_32x32x16_bf16(Al, XF[kc][0], S, 0, 0, 0);
        }
        if (w == 0 && lane < 32) nrmL[lane] = norms[(b0 + it) * 32 + lane];
        float* rowp = slots + l31 * 33;   // row = q
        #pragma unroll
        for (int r = 0; r < 16; r++) {
            int n = (r & 3) + 8 * (r >> 2) + 4 * half;
            atomicAdd(rowp + n, S[r]);
        }
        __syncthreads();   // (b) S reduced, nrm ready

        if (w < 4) {       // ---- softmax -> Pb (bf16), re-zero slots ----
            int ql = lane >> 3, nq = lane & 7;
            int q = w * 8 + ql;
            float c1q = c1A[q], c2q = c2A[q];
            float lg[4];
            float mt = -1e30f;
            #pragma unroll
            for (int j = 0; j < 4; j++) {
                int n = nq * 4 + j;
                float dd = slots[q * 33 + n];
                slots[q * 33 + n] = 0.0f;
                lg[j] = c1q * dd - c2q * nrmL[n];
                mt = fmaxf(mt, lg[j]);
            }
            mt = fmaxf(mt, __shfl_xor(mt, 1, 64));
            mt = fmaxf(mt, __shfl_xor(mt, 2, 64));
            mt = fmaxf(mt, __shfl_xor(mt, 4, 64));
            float mo = mAs[q];
            float mn = fmaxf(mo, mt);
            float al = __expf(mo - mn);
            float ls = 0.f;
            unsigned pk[4];
            #pragma unroll
            for (int j = 0; j < 4; j++) {
                float p = __expf(lg[j] - mn);
                ls += p;
                pk[j] = f2bf(p);
            }
            ls += __shfl_xor(ls, 1, 64);
            ls += __shfl_xor(ls, 2, 64);
            ls += __shfl_xor(ls, 4, 64);
            *(uint2*)(Pb + ((nq >> 1) * 32 + q) * 8 + (nq & 1) * 4) =
                make_uint2(pk[0] | (pk[1] << 16), pk[2] | (pk[3] << 16));
            if (nq == 0) {
                mAs[q] = mn;
                lAs[q] = lAs[q] * al + ls;
                alA[q] = al;
            }
        }
        __syncthreads();   // (c) Pb/alpha ready, slots zeroed

        // ---- PV phase: d-slice [w*64, w*64+64) ----
        {
            const short* yb = Yt + tb;
            float al = alA[l31];
            short8 BF[2];
            #pragma unroll
            for (int kc = 0; kc < 2; kc++)
                BF[kc] = *(const short8*)(Pb + ((kc * 2 + half) * 32 + l31) * 8);
            O[0] *= al;
            O[1] *= al;
            #pragma unroll
            for (int dt = 0; dt < 2; dt++) {
                #pragma unroll
                for (int kc = 0; kc < 2; kc++) {
                    short8 AF = *(const short8*)(
                        yb + (w * 64 + dt * 32 + l31) * 32 + kc * 16 + half * 8);
                    O[dt] = __builtin_amdgcn_mfma_f32_32x32x16_bf16(
                        AF, BF[kc], O[dt], 0, 0, 0);
                }
            }
        }
    }

    if (tid < 32) {
        m_part[(size_t)s * B_SZ + qb + tid] = mAs[tid];
        l_part[(size_t)s * B_SZ + qb + tid] = lAs[tid];
    }
    #pragma unroll
    for (int dt = 0; dt < 2; dt++) {
        float* op = acc_part + ((size_t)s * B_SZ + qb + l31) * D_SZ
                  + w * 64 + dt * 32 + 4 * half;
        #pragma unroll
        for (int rg = 0; rg < 4; rg++) {
            float4 v = make_float4(O[dt][4 * rg], O[dt][4 * rg + 1],
                                   O[dt][4 * rg + 2], O[dt][4 * rg + 3]);
            *(float4*)(op + 8 * rg) = v;
        }
    }
}

// ---------------- COMBINE: merge splits + epilogue ----------------
__global__ __launch_bounds__(256) void combine_kernel(
    const float* __restrict__ x_t, const float* __restrict__ t,
    const float* __restrict__ m_part, const float* __restrict__ l_part,
    const float* __restrict__ acc_part, float* __restrict__ out, int nsplit)
{
    int q = blockIdx.x;
    int tid = threadIdx.x;
    float M = -1e30f;
    for (int s = 0; s < nsplit; s++) M = fmaxf(M, m_part[(size_t)s * B_SZ + q]);
    float L = 0.f;
    for (int s = 0; s < nsplit; s++)
        L += l_part[(size_t)s * B_SZ + q] * __expf(m_part[(size_t)s * B_SZ + q] - M);

    float tv = t[q];
    float bt = 1.0f - tv;
    float coeff = 1.0f + tv / bt;
    float invb = 1.0f / bt;
    float invL = 1.0f / L;

    int d = tid * 2;
    float2 w = make_float2(0.f, 0.f);
    for (int s = 0; s < nsplit; s++) {
        float sc = __expf(m_part[(size_t)s * B_SZ + q] - M);
        float2 av = *(const float2*)(acc_part + ((size_t)s * B_SZ + q) * D_SZ + d);
        w.x += sc * av.x; w.y += sc * av.y;
    }
    float2 xv = *(const float2*)(x_t + (size_t)q * D_SZ + d);
    float2 o;
    o.x = -invb * xv.x + coeff * w.x * invL;
    o.y = -invb * xv.y + coeff * w.y * invL;
    *(float2*)(out + (size_t)q * D_SZ + d) = o;
}

extern "C" void kernel_launch(void* const* d_in, const int* in_sizes, int n_in,
                              void* d_out, int out_size, void* d_ws, size_t ws_size,
                              hipStream_t stream) {
    const float* x_t = (const float*)d_in[0];
    const float* t   = (const float*)d_in[1];
    const float* ds  = (const float*)d_in[2];
    float* out = (float*)d_out;

    short* wsS = (short*)d_ws;
    short* Ysh = wsS;                             // 51,200,000 shorts
    short* Ysl = wsS + 51200000;
    short* Yt  = wsS + 102400000;
    short* Xh  = wsS + 153600000;                 // 524,288 shorts
    short* Xl  = wsS + 154124288;
    float* fbase = (float*)((char*)d_ws + 309297152);   // 16B-aligned
    float* norms = fbase;                         // 100,000 f32
    int nsplit = 16;
    while (nsplit > 1 &&
           309697152ULL + (size_t)nsplit * 1024 * 4 * (2 + 512) > ws_size)
        nsplit >>= 1;
    float* m_part = fbase + 100000;
    float* l_part = m_part + (size_t)nsplit * B_SZ;
    float* acc    = l_part + (size_t)nsplit * B_SZ;
    int chunk = 32 * ((N_SZ + 32 * nsplit - 1) / (32 * nsplit));

    pre_kernel<<<dim3(NBLK + 32), dim3(256), 0, stream>>>(ds, x_t, Ysh, Ysl, Yt, Xh, Xl, norms);
    attn_kernel<<<dim3(B_SZ / 32, nsplit), dim3(512), 0, stream>>>(
        t, Xh, Xl, Ysh, Ysl, Yt, norms, m_part, l_part, acc, chunk);
    combine_kernel<<<dim3(B_SZ), dim3(256), 0, stream>>>(
        x_t, t, m_part, l_part, acc, out, nsplit);
}